// Round 18
// baseline (194.326 us; speedup 1.0000x reference)
//
#include <hip/hip_runtime.h>

typedef unsigned short u16;
typedef unsigned int u32;
typedef unsigned long long u64;
typedef __attribute__((ext_vector_type(4))) float f32x4;
typedef __attribute__((ext_vector_type(8))) short bf16x8;
typedef __attribute__((ext_vector_type(4))) u32 u32x4;

// ============================================================================
// SESSION LEDGER (R0-R17, best = 189.0 us; noise band +-2%):
//   R1 328 -> R2 259.7 (attn occupancy+bitmask) -> R3 245.2 (T2 swizzle, conflicts
//   2.1e7->0) -> R8 204.1 (attn swapped-QKT) -> R10 196.9 (fused convert + v5 attn
//   + ballot mask) -> R16 189.0 (fused prep launch). R17 identical re-run: 193.3
//   (noise; counters byte-identical).
//   FAILED (do not retry): R4 coarse 8-phase GEMM; R7 counted 4-phase (141);
//   R9 depth-2 A-reg prefetch (scratch spill, WRITE 110->287MB); R11 256x128
//   8-wave (137); R13 full-dbuf 2 blocks/CU (132); R12 attn 9-wave/1-tile (+11);
//   R14 exp2f for __expf (+11: exp2f = PRECISE libm entry without -ffast-math).
//   Mechanism: at 3 blocks/CU the inter-block wave overlap (m114) hides the
//   2-phase drain better than any source-level intra-block pipeline attempted.
//   NOT a HW roofline (MfmaUtil 21%, HBM 24%): path beyond GEMM1's ~111us is the
//   exact 8-phase derived-waits template (needs interactive asm/A-B iteration).
// ============================================================================

__device__ __forceinline__ u16 f2bf(float f) {
  union { float f; u32 u; } v; v.f = f;
  u32 r = v.u + 0x7fffu + ((v.u >> 16) & 1u);
  return (u16)(r >> 16);
}

// RNE bf16 via HW cvt (1 VALU); store of u16 takes low half directly.
__device__ __forceinline__ u16 f2bf_rne(float f) {
  u32 w;
  asm("v_cvt_pk_bf16_f32 %0, %1, %2" : "=v"(w) : "v"(f), "v"(f));
  return (u16)w;
}

__device__ __forceinline__ void gload_lds16(const u16* g, u16* l) {
  __builtin_amdgcn_global_load_lds((__attribute__((address_space(1))) const void*)g,
                                   (__attribute__((address_space(3))) void*)l,
                                   16, 0, 0);
}

// ---------------- fused prep: weight transposes + mask bitmask in ONE launch ----------------
__device__ __forceinline__ void transpose_tile(const float* __restrict__ W,
                                               u16* __restrict__ Wt, int K, int Nc,
                                               int kb, int nb, int tid) {
  __shared__ u16 t[64][72];  // [k][n], +8 pad
  const int c4 = (tid & 15) * 4;
  const int r0 = tid >> 4;
#pragma unroll
  for (int rr = 0; rr < 4; ++rr) {
    int r = rr * 16 + r0;
    float4 v = *(const float4*)(W + (size_t)(kb + r) * Nc + nb + c4);
    t[r][c4 + 0] = f2bf(v.x);
    t[r][c4 + 1] = f2bf(v.y);
    t[r][c4 + 2] = f2bf(v.z);
    t[r][c4 + 3] = f2bf(v.w);
  }
  __syncthreads();
  const int c8 = (tid & 7) * 8;
  const int rn = tid >> 3;
#pragma unroll
  for (int rr = 0; rr < 2; ++rr) {
    int n = rr * 32 + rn;
    u16 tmp[8];
#pragma unroll
    for (int j = 0; j < 8; ++j) tmp[j] = t[c8 + j][n];
    *(u32x4*)(Wt + (size_t)(nb + n) * K + kb + c8) = *(const u32x4*)tmp;
  }
}

__global__ void __launch_bounds__(256) k_prep(const float* __restrict__ Wqkv,
                                              const float* __restrict__ Wproj,
                                              const int* __restrict__ mask,
                                              u16* __restrict__ wqkv_t,
                                              u16* __restrict__ wproj_t,
                                              u32* __restrict__ mtab) {
  const int b = blockIdx.x;
  const int tid = threadIdx.x;
  if (b < 192) {
    transpose_tile(Wqkv, wqkv_t, 512, 1536, (b & 7) * 64, (b >> 3) * 64, tid);
  } else if (b < 256) {
    const int bb = b - 192;  // 8 x 8 grid
    transpose_tile(Wproj, wproj_t, 512, 512, (bb & 7) * 64, (bb >> 3) * 64, tid);
  } else {
    const int row = (b - 256) * 4 + (tid >> 6);  // 9216 rows = 64*144
    const int lane = tid & 63;
    const int* base = mask + (size_t)row * 144;
    u64 b01 = __ballot(base[lane] != 0);        // cols 0..63
    u64 b23 = __ballot(base[64 + lane] != 0);   // cols 64..127
    int v4 = (lane < 16) ? base[128 + lane] : 0;
    u64 b4 = __ballot(v4 != 0);                 // cols 128..143
    if (lane == 0) {
      u32* o = mtab + (size_t)row * 8;
      o[0] = (u32)b01; o[1] = (u32)(b01 >> 32);
      o[2] = (u32)b23; o[3] = (u32)(b23 >> 32);
      o[4] = (u32)b4;  o[5] = 0; o[6] = 0; o[7] = 0;
    }
  }
}

// ---------------- GEMM (best measured): 128x128, BK=64, 4 waves, 3 blocks/CU ----------------
// A: global (fp32->cvt | bf16) -> regs (issued iter t-1) -> ds_write into padded As[128][68].
// B: gload_lds, double-buffered, chunk-XOR source swizzle (0 conflicts).
// One vmcnt(0)+lgkmcnt(0) per iter, raw s_barrier. LDS 50,176 B -> 3 blocks/CU.
template <bool OUT_BF16, bool A_FP32>
__global__ void __launch_bounds__(256, 3) k_gemm(const void* __restrict__ Ap,
                                                 const u16* __restrict__ Bt,
                                                 const float* __restrict__ bias,
                                                 void* __restrict__ D,
                                                 int Nc, int K, int NB) {
  __shared__ u16 As[128 * 68];      // row stride 68 u16 = 136 B (pad +4)
  __shared__ u16 Bs[2][128 * 64];   // linear dest, chunk-XOR swizzled source
  const int tid = threadIdx.x;
  const int wave = tid >> 6, lane = tid & 63;
  const int wr = wave >> 1, wc = wave & 1;
  const int l15 = lane & 15, g = lane >> 4;
  const int sx = l15 & 7;
  const f32x4 fzero = {0.f, 0.f, 0.f, 0.f};

  const int cpx = gridDim.x >> 3;
  const int swz = (blockIdx.x & 7) * cpx + (blockIdx.x >> 3);
  const int bm = swz / NB, bn = swz % NB;

  const u16* Bb = Bt + (size_t)bn * 128 * K;

  int rr[4], cc[4];
#pragma unroll
  for (int i = 0; i < 4; ++i) {
    int e = i * 256 + tid;
    rr[i] = e >> 3;
    cc[i] = e & 7;
  }

  f32x4 acc[4][4];
#pragma unroll
  for (int m = 0; m < 4; ++m)
#pragma unroll
    for (int n = 0; n < 4; ++n) acc[m][n] = fzero;

  f32x4 areg[8];
  u32x4 aregb[4];

  auto A_LOAD = [&](int ks) {
    if constexpr (A_FP32) {
      const float* Af = (const float*)Ap;
#pragma unroll
      for (int i = 0; i < 4; ++i) {
        const float* p = Af + (size_t)(bm * 128 + rr[i]) * K + ks + cc[i] * 8;
        areg[2 * i] = *(const f32x4*)(p);
        areg[2 * i + 1] = *(const f32x4*)(p + 4);
      }
    } else {
      const u16* Ab = (const u16*)Ap + (size_t)bm * 128 * K;
#pragma unroll
      for (int i = 0; i < 4; ++i)
        aregb[i] = *(const u32x4*)(Ab + (size_t)rr[i] * K + ks + cc[i] * 8);
    }
  };

  auto A_WRITE = [&]() {
#pragma unroll
    for (int i = 0; i < 4; ++i) {
      u32x4 wv;
      if constexpr (A_FP32) {
        u32 w0, w1, w2, w3;
        asm("v_cvt_pk_bf16_f32 %0, %1, %2" : "=v"(w0) : "v"(areg[2 * i][0]), "v"(areg[2 * i][1]));
        asm("v_cvt_pk_bf16_f32 %0, %1, %2" : "=v"(w1) : "v"(areg[2 * i][2]), "v"(areg[2 * i][3]));
        asm("v_cvt_pk_bf16_f32 %0, %1, %2" : "=v"(w2) : "v"(areg[2 * i + 1][0]), "v"(areg[2 * i + 1][1]));
        asm("v_cvt_pk_bf16_f32 %0, %1, %2" : "=v"(w3) : "v"(areg[2 * i + 1][2]), "v"(areg[2 * i + 1][3]));
        wv[0] = w0; wv[1] = w1; wv[2] = w2; wv[3] = w3;
      } else {
        wv = aregb[i];
      }
      *(u32x4*)(&As[rr[i] * 68 + cc[i] * 8]) = wv;
    }
  };

  auto B_STAGE = [&](int buf, int ks) {
#pragma unroll
    for (int i = 0; i < 4; ++i) {
      int cs = cc[i] ^ (rr[i] & 7);
      gload_lds16(Bb + (size_t)rr[i] * K + ks + (cs << 3), &Bs[buf][(i * 256 + tid) * 8]);
    }
  };

  auto COMPUTE = [&](int buf) {
#pragma unroll
    for (int kk = 0; kk < 2; ++kk) {
      bf16x8 a[4], b[4];
#pragma unroll
      for (int m = 0; m < 4; ++m)
        a[m] = *(const bf16x8*)(&As[(wr * 64 + m * 16 + l15) * 68 + (kk * 4 + g) * 8]);
#pragma unroll
      for (int n = 0; n < 4; ++n)
        b[n] = *(const bf16x8*)(&Bs[buf][(wc * 64 + n * 16 + l15) * 64 + (((kk * 4 + g) ^ sx) << 3)]);
#pragma unroll
      for (int m = 0; m < 4; ++m)
#pragma unroll
        for (int n = 0; n < 4; ++n)
          acc[m][n] = __builtin_amdgcn_mfma_f32_16x16x32_bf16(a[m], b[n], acc[m][n], 0, 0, 0);
    }
  };

  const int nt = K >> 6;
  A_LOAD(0);
  B_STAGE(0, 0);
  int cur = 0;
  for (int t = 0; t < nt; ++t) {
    asm volatile("s_waitcnt vmcnt(0)" ::: "memory");
    __builtin_amdgcn_sched_barrier(0);
    if (t + 1 < nt) B_STAGE(cur ^ 1, (t + 1) << 6);
    A_WRITE();
    if (t + 1 < nt) A_LOAD((t + 1) << 6);
    asm volatile("s_waitcnt lgkmcnt(0)" ::: "memory");
    __builtin_amdgcn_sched_barrier(0);
    __builtin_amdgcn_s_barrier();
    __builtin_amdgcn_sched_barrier(0);
    COMPUTE(cur);
    __builtin_amdgcn_sched_barrier(0);
    if (t + 1 < nt) __builtin_amdgcn_s_barrier();
    cur ^= 1;
  }

  const int row0 = bm * 128 + wr * 64;
  const int col0 = bn * 128 + wc * 64;
#pragma unroll
  for (int m = 0; m < 4; ++m) {
#pragma unroll
    for (int n = 0; n < 4; ++n) {
      int col = col0 + n * 16 + l15;
      float bv = bias[col];
#pragma unroll
      for (int j = 0; j < 4; ++j) {
        int row = row0 + m * 16 + g * 4 + j;
        float v = acc[m][n][j] + bv;
        if constexpr (OUT_BF16)
          ((u16*)D)[(size_t)row * Nc + col] = f2bf_rne(v);
        else
          ((float*)D)[(size_t)row * Nc + col] = v;
      }
    }
  }
}

// ---------------- Window attention v5 (best measured) ----------------
// 192 threads (3 waves, 3 mt-tiles each). Swapped QK^T; no-max-sub softmax via __expf
// (fast path). Pipelined: QKT(it+1) in ds_write shadow; SM(it+1) after PV(it);
// setprio around PV MFMA cluster.
__global__ void __launch_bounds__(192) k_attn(const u16* __restrict__ qkv,
                                              const u32* __restrict__ mtab,
                                              u16* __restrict__ obuf) {
  __shared__ u16 k_s[144 * 40];      // [n][d] +8 pad
  __shared__ u16 vT_s[32 * 168];     // [d][k] k padded to 160 (+8)
  __shared__ u16 P_s[3][16 * 168];   // per-wave [q][k], k padded to 160 (+8)

  const int bh = blockIdx.x;
  const int bn = bh >> 4, h = bh & 15;
  const int wid = bn & 63;
  const int tid = threadIdx.x;
  const int wave = tid >> 6, lane = tid & 63;
  const int l15 = lane & 15, g = lane >> 4;
  const f32x4 fzero = {0.f, 0.f, 0.f, 0.f};

  const u16* base = qkv + (size_t)bn * 144 * 1536 + h * 32;
  u16* Pw = &P_s[wave][0];

  bf16x8 qb[3];
  u32 mw[3][5];
#pragma unroll
  for (int it = 0; it < 3; ++it) {
    const int mt = wave + it * 3;
    qb[it] = *(const bf16x8*)(base + (size_t)(mt * 16 + l15) * 1536 + g * 8);
    const u32* mp = mtab + ((size_t)(wid * 144 + mt * 16 + l15) << 3);
#pragma unroll
    for (int wd = 0; wd < 5; ++wd) mw[it][wd] = mp[wd];
  }

  *(u32*)(Pw + l15 * 168 + 144 + g * 4) = 0;
  *(u32*)(Pw + l15 * 168 + 144 + g * 4 + 2) = 0;

  for (int e = tid; e < 576; e += 192) {
    int n = e >> 2, c = e & 3;
    const u16* rowp = base + (size_t)n * 1536 + c * 8;
    u32x4 kv = *(const u32x4*)(rowp + 512);
    u32x4 vv = *(const u32x4*)(rowp + 1024);
    *(u32x4*)(k_s + n * 40 + c * 8) = kv;
#pragma unroll
    for (int t = 0; t < 4; ++t) {
      u32 w = vv[t];
      vT_s[(c * 8 + 2 * t) * 168 + n] = (u16)(w & 0xffffu);
      vT_s[(c * 8 + 2 * t + 1) * 168 + n] = (u16)(w >> 16);
    }
  }
  for (int e = tid; e < 512; e += 192) {
    int d = e >> 4, c = e & 15;
    vT_s[d * 168 + 144 + c] = 0;
  }
  __syncthreads();

  const float scale = 0.17677669529663687f;  // 1/sqrt(32)

  f32x4 accs[9];
  float rinv;

#define QKT(IT)                                                                  \
  {                                                                              \
    _Pragma("unroll") for (int nt = 0; nt < 9; ++nt) {                           \
      bf16x8 kf = *(const bf16x8*)(k_s + (nt * 16 + l15) * 40 + g * 8);          \
      accs[nt] = __builtin_amdgcn_mfma_f32_16x16x32_bf16(kf, qb[IT], fzero, 0, 0, 0); \
    }                                                                            \
  }
#define SM(IT)                                                                   \
  {                                                                              \
    float rsum = 0.f;                                                            \
    _Pragma("unroll") for (int nt = 0; nt < 9; ++nt) {                           \
      const int wd = nt >> 1;                                                    \
      const int shb = (nt & 1) * 16;                                             \
      _Pragma("unroll") for (int j = 0; j < 4; ++j) {                            \
        float e = __expf(accs[nt][j] * scale);                                   \
        u32 bit = (mw[IT][wd] >> (shb + g * 4 + j)) & 1u;                        \
        e = bit ? e : 0.f;                                                       \
        accs[nt][j] = e;                                                         \
        rsum += e;                                                               \
      }                                                                          \
    }                                                                            \
    rsum += __shfl_xor(rsum, 16, 64);                                            \
    rsum += __shfl_xor(rsum, 32, 64);                                            \
    rinv = 1.f / rsum;                                                           \
  }

  QKT(0);
  SM(0);

#pragma unroll
  for (int it = 0; it < 3; ++it) {
    const int mt = wave + it * 3;

#pragma unroll
    for (int nt = 0; nt < 9; ++nt) {
      u32 w0, w1;
      float p0 = accs[nt][0] * rinv, p1 = accs[nt][1] * rinv;
      float p2 = accs[nt][2] * rinv, p3 = accs[nt][3] * rinv;
      asm("v_cvt_pk_bf16_f32 %0, %1, %2" : "=v"(w0) : "v"(p0), "v"(p1));
      asm("v_cvt_pk_bf16_f32 %0, %1, %2" : "=v"(w1) : "v"(p2), "v"(p3));
      *(u32*)(Pw + l15 * 168 + nt * 16 + g * 4) = w0;
      *(u32*)(Pw + l15 * 168 + nt * 16 + g * 4 + 2) = w1;
    }

    if (it == 0) QKT(1);
    if (it == 1) QKT(2);

    asm volatile("s_waitcnt lgkmcnt(0)" ::: "memory");
    __builtin_amdgcn_sched_barrier(0);

    f32x4 acco[2];
    acco[0] = fzero;
    acco[1] = fzero;
    __builtin_amdgcn_s_setprio(1);
#pragma unroll
    for (int kk = 0; kk < 5; ++kk) {
      bf16x8 pa = *(const bf16x8*)(Pw + l15 * 168 + kk * 32 + g * 8);
#pragma unroll
      for (int nt2 = 0; nt2 < 2; ++nt2) {
        bf16x8 b = *(const bf16x8*)(vT_s + (nt2 * 16 + l15) * 168 + kk * 32 + g * 8);
        acco[nt2] = __builtin_amdgcn_mfma_f32_16x16x32_bf16(pa, b, acco[nt2], 0, 0, 0);
      }
    }
    __builtin_amdgcn_s_setprio(0);

    if (it == 0) SM(1);
    if (it == 1) SM(2);

#pragma unroll
    for (int nt2 = 0; nt2 < 2; ++nt2)
#pragma unroll
      for (int j = 0; j < 4; ++j) {
        int r = mt * 16 + g * 4 + j;
        int d = nt2 * 16 + l15;
        obuf[((size_t)bn * 144 + r) * 512 + h * 32 + d] = f2bf_rne(acco[nt2][j]);
      }
  }
#undef QKT
#undef SM
}

extern "C" void kernel_launch(void* const* d_in, const int* in_sizes, int n_in,
                              void* d_out, int out_size, void* d_ws, size_t ws_size,
                              hipStream_t stream) {
  const float* x = (const float*)d_in[0];
  const int* mask = (const int*)d_in[1];
  const float* Wqkv = (const float*)d_in[2];
  const float* bqkv = (const float*)d_in[3];
  const float* Wproj = (const float*)d_in[4];
  const float* bproj = (const float*)d_in[5];
  float* out = (float*)d_out;

  char* ws = (char*)d_ws;
  u32* mtab    = (u32*)(ws + 0);          //     294,912 B
  u16* wqkv_t  = (u16*)(ws + 294912);     //   1,572,864 B
  u16* qkv     = (u16*)(ws + 1867776);    // 113,246,208 B
  u16* obuf    = (u16*)(ws + 115113984);  //  37,748,736 B
  u16* wproj_t = (u16*)(ws + 152862720);  //     524,288 B  (total 153,387,008)

  // 1) fused prep: both weight transposes + mask bitmask (one launch)
  k_prep<<<2560, 256, 0, stream>>>(Wqkv, Wproj, mask, wqkv_t, wproj_t, mtab);
  // 2) qkv = x @ Wqkv + bqkv (bf16 out); A = fp32 x converted in-kernel.
  k_gemm<true, true><<<3456, 256, 0, stream>>>(x, wqkv_t, bqkv, qkv, 1536, 512, 12);
  // 3) window attention (192 threads = 3 waves, pipelined v5)
  k_attn<<<4096, 192, 0, stream>>>(qkv, mtab, obuf);
  // 4) out = O @ Wproj + bproj (fp32 out)
  k_gemm<false, false><<<1152, 256, 0, stream>>>(obuf, wproj_t, bproj, out, 512, 512, 4);
}

// Round 19
// 193.770 us; speedup vs baseline: 1.0029x; 1.0029x over previous
//
#include <hip/hip_runtime.h>

typedef unsigned short u16;
typedef unsigned int u32;
typedef unsigned long long u64;
typedef __attribute__((ext_vector_type(4))) float f32x4;
typedef __attribute__((ext_vector_type(8))) short bf16x8;
typedef __attribute__((ext_vector_type(4))) u32 u32x4;

// ============================================================================
// SESSION LEDGER (R0-R18, best = 189.0 us; noise band +-2-3%):
//   R1 328 -> R2 259.7 (attn occupancy+bitmask) -> R3 245.2 (T2 swizzle, conflicts
//   2.1e7->0) -> R8 204.1 (attn swapped-QKT) -> R10 196.9 (fused convert + v5 attn
//   + ballot mask) -> R16 189.0 (fused prep launch). R17/R18 identical re-runs:
//   193.3 / 194.3 (noise; counters byte-identical).
//   FAILED (do not retry): R4 coarse 8-phase GEMM; R7 counted 4-phase (141);
//   R9 depth-2 A-reg prefetch (scratch spill, WRITE 110->287MB); R11 256x128
//   8-wave (137); R13 full-dbuf 2 blocks/CU (132); R12 attn 9-wave/1-tile (+11);
//   R14 exp2f for __expf (+11: exp2f = PRECISE libm entry without -ffast-math).
//   Mechanism: at 3 blocks/CU the inter-block wave overlap (m114) hides the
//   2-phase drain better than any source-level intra-block pipeline attempted.
//   NOT a HW roofline (MfmaUtil 21%, HBM ~19%): path beyond GEMM1's ~111us is the
//   exact 8-phase derived-waits template (needs interactive asm/A-B iteration).
// ============================================================================

__device__ __forceinline__ u16 f2bf(float f) {
  union { float f; u32 u; } v; v.f = f;
  u32 r = v.u + 0x7fffu + ((v.u >> 16) & 1u);
  return (u16)(r >> 16);
}

// RNE bf16 via HW cvt (1 VALU); store of u16 takes low half directly.
__device__ __forceinline__ u16 f2bf_rne(float f) {
  u32 w;
  asm("v_cvt_pk_bf16_f32 %0, %1, %2" : "=v"(w) : "v"(f), "v"(f));
  return (u16)w;
}

__device__ __forceinline__ void gload_lds16(const u16* g, u16* l) {
  __builtin_amdgcn_global_load_lds((__attribute__((address_space(1))) const void*)g,
                                   (__attribute__((address_space(3))) void*)l,
                                   16, 0, 0);
}

// ---------------- fused prep: weight transposes + mask bitmask in ONE launch ----------------
__device__ __forceinline__ void transpose_tile(const float* __restrict__ W,
                                               u16* __restrict__ Wt, int K, int Nc,
                                               int kb, int nb, int tid) {
  __shared__ u16 t[64][72];  // [k][n], +8 pad
  const int c4 = (tid & 15) * 4;
  const int r0 = tid >> 4;
#pragma unroll
  for (int rr = 0; rr < 4; ++rr) {
    int r = rr * 16 + r0;
    float4 v = *(const float4*)(W + (size_t)(kb + r) * Nc + nb + c4);
    t[r][c4 + 0] = f2bf(v.x);
    t[r][c4 + 1] = f2bf(v.y);
    t[r][c4 + 2] = f2bf(v.z);
    t[r][c4 + 3] = f2bf(v.w);
  }
  __syncthreads();
  const int c8 = (tid & 7) * 8;
  const int rn = tid >> 3;
#pragma unroll
  for (int rr = 0; rr < 2; ++rr) {
    int n = rr * 32 + rn;
    u16 tmp[8];
#pragma unroll
    for (int j = 0; j < 8; ++j) tmp[j] = t[c8 + j][n];
    *(u32x4*)(Wt + (size_t)(nb + n) * K + kb + c8) = *(const u32x4*)tmp;
  }
}

__global__ void __launch_bounds__(256) k_prep(const float* __restrict__ Wqkv,
                                              const float* __restrict__ Wproj,
                                              const int* __restrict__ mask,
                                              u16* __restrict__ wqkv_t,
                                              u16* __restrict__ wproj_t,
                                              u32* __restrict__ mtab) {
  const int b = blockIdx.x;
  const int tid = threadIdx.x;
  if (b < 192) {
    transpose_tile(Wqkv, wqkv_t, 512, 1536, (b & 7) * 64, (b >> 3) * 64, tid);
  } else if (b < 256) {
    const int bb = b - 192;  // 8 x 8 grid
    transpose_tile(Wproj, wproj_t, 512, 512, (bb & 7) * 64, (bb >> 3) * 64, tid);
  } else {
    const int row = (b - 256) * 4 + (tid >> 6);  // 9216 rows = 64*144
    const int lane = tid & 63;
    const int* base = mask + (size_t)row * 144;
    u64 b01 = __ballot(base[lane] != 0);        // cols 0..63
    u64 b23 = __ballot(base[64 + lane] != 0);   // cols 64..127
    int v4 = (lane < 16) ? base[128 + lane] : 0;
    u64 b4 = __ballot(v4 != 0);                 // cols 128..143
    if (lane == 0) {
      u32* o = mtab + (size_t)row * 8;
      o[0] = (u32)b01; o[1] = (u32)(b01 >> 32);
      o[2] = (u32)b23; o[3] = (u32)(b23 >> 32);
      o[4] = (u32)b4;  o[5] = 0; o[6] = 0; o[7] = 0;
    }
  }
}

// ---------------- GEMM (best measured): 128x128, BK=64, 4 waves, 3 blocks/CU ----------------
// A: global (fp32->cvt | bf16) -> regs (issued iter t-1) -> ds_write into padded As[128][68].
// B: gload_lds, double-buffered, chunk-XOR source swizzle (0 conflicts).
// One vmcnt(0)+lgkmcnt(0) per iter, raw s_barrier. LDS 50,176 B -> 3 blocks/CU.
template <bool OUT_BF16, bool A_FP32>
__global__ void __launch_bounds__(256, 3) k_gemm(const void* __restrict__ Ap,
                                                 const u16* __restrict__ Bt,
                                                 const float* __restrict__ bias,
                                                 void* __restrict__ D,
                                                 int Nc, int K, int NB) {
  __shared__ u16 As[128 * 68];      // row stride 68 u16 = 136 B (pad +4)
  __shared__ u16 Bs[2][128 * 64];   // linear dest, chunk-XOR swizzled source
  const int tid = threadIdx.x;
  const int wave = tid >> 6, lane = tid & 63;
  const int wr = wave >> 1, wc = wave & 1;
  const int l15 = lane & 15, g = lane >> 4;
  const int sx = l15 & 7;
  const f32x4 fzero = {0.f, 0.f, 0.f, 0.f};

  const int cpx = gridDim.x >> 3;
  const int swz = (blockIdx.x & 7) * cpx + (blockIdx.x >> 3);
  const int bm = swz / NB, bn = swz % NB;

  const u16* Bb = Bt + (size_t)bn * 128 * K;

  int rr[4], cc[4];
#pragma unroll
  for (int i = 0; i < 4; ++i) {
    int e = i * 256 + tid;
    rr[i] = e >> 3;
    cc[i] = e & 7;
  }

  f32x4 acc[4][4];
#pragma unroll
  for (int m = 0; m < 4; ++m)
#pragma unroll
    for (int n = 0; n < 4; ++n) acc[m][n] = fzero;

  f32x4 areg[8];
  u32x4 aregb[4];

  auto A_LOAD = [&](int ks) {
    if constexpr (A_FP32) {
      const float* Af = (const float*)Ap;
#pragma unroll
      for (int i = 0; i < 4; ++i) {
        const float* p = Af + (size_t)(bm * 128 + rr[i]) * K + ks + cc[i] * 8;
        areg[2 * i] = *(const f32x4*)(p);
        areg[2 * i + 1] = *(const f32x4*)(p + 4);
      }
    } else {
      const u16* Ab = (const u16*)Ap + (size_t)bm * 128 * K;
#pragma unroll
      for (int i = 0; i < 4; ++i)
        aregb[i] = *(const u32x4*)(Ab + (size_t)rr[i] * K + ks + cc[i] * 8);
    }
  };

  auto A_WRITE = [&]() {
#pragma unroll
    for (int i = 0; i < 4; ++i) {
      u32x4 wv;
      if constexpr (A_FP32) {
        u32 w0, w1, w2, w3;
        asm("v_cvt_pk_bf16_f32 %0, %1, %2" : "=v"(w0) : "v"(areg[2 * i][0]), "v"(areg[2 * i][1]));
        asm("v_cvt_pk_bf16_f32 %0, %1, %2" : "=v"(w1) : "v"(areg[2 * i][2]), "v"(areg[2 * i][3]));
        asm("v_cvt_pk_bf16_f32 %0, %1, %2" : "=v"(w2) : "v"(areg[2 * i + 1][0]), "v"(areg[2 * i + 1][1]));
        asm("v_cvt_pk_bf16_f32 %0, %1, %2" : "=v"(w3) : "v"(areg[2 * i + 1][2]), "v"(areg[2 * i + 1][3]));
        wv[0] = w0; wv[1] = w1; wv[2] = w2; wv[3] = w3;
      } else {
        wv = aregb[i];
      }
      *(u32x4*)(&As[rr[i] * 68 + cc[i] * 8]) = wv;
    }
  };

  auto B_STAGE = [&](int buf, int ks) {
#pragma unroll
    for (int i = 0; i < 4; ++i) {
      int cs = cc[i] ^ (rr[i] & 7);
      gload_lds16(Bb + (size_t)rr[i] * K + ks + (cs << 3), &Bs[buf][(i * 256 + tid) * 8]);
    }
  };

  auto COMPUTE = [&](int buf) {
#pragma unroll
    for (int kk = 0; kk < 2; ++kk) {
      bf16x8 a[4], b[4];
#pragma unroll
      for (int m = 0; m < 4; ++m)
        a[m] = *(const bf16x8*)(&As[(wr * 64 + m * 16 + l15) * 68 + (kk * 4 + g) * 8]);
#pragma unroll
      for (int n = 0; n < 4; ++n)
        b[n] = *(const bf16x8*)(&Bs[buf][(wc * 64 + n * 16 + l15) * 64 + (((kk * 4 + g) ^ sx) << 3)]);
#pragma unroll
      for (int m = 0; m < 4; ++m)
#pragma unroll
        for (int n = 0; n < 4; ++n)
          acc[m][n] = __builtin_amdgcn_mfma_f32_16x16x32_bf16(a[m], b[n], acc[m][n], 0, 0, 0);
    }
  };

  const int nt = K >> 6;
  A_LOAD(0);
  B_STAGE(0, 0);
  int cur = 0;
  for (int t = 0; t < nt; ++t) {
    asm volatile("s_waitcnt vmcnt(0)" ::: "memory");
    __builtin_amdgcn_sched_barrier(0);
    if (t + 1 < nt) B_STAGE(cur ^ 1, (t + 1) << 6);
    A_WRITE();
    if (t + 1 < nt) A_LOAD((t + 1) << 6);
    asm volatile("s_waitcnt lgkmcnt(0)" ::: "memory");
    __builtin_amdgcn_sched_barrier(0);
    __builtin_amdgcn_s_barrier();
    __builtin_amdgcn_sched_barrier(0);
    COMPUTE(cur);
    __builtin_amdgcn_sched_barrier(0);
    if (t + 1 < nt) __builtin_amdgcn_s_barrier();
    cur ^= 1;
  }

  const int row0 = bm * 128 + wr * 64;
  const int col0 = bn * 128 + wc * 64;
#pragma unroll
  for (int m = 0; m < 4; ++m) {
#pragma unroll
    for (int n = 0; n < 4; ++n) {
      int col = col0 + n * 16 + l15;
      float bv = bias[col];
#pragma unroll
      for (int j = 0; j < 4; ++j) {
        int row = row0 + m * 16 + g * 4 + j;
        float v = acc[m][n][j] + bv;
        if constexpr (OUT_BF16)
          ((u16*)D)[(size_t)row * Nc + col] = f2bf_rne(v);
        else
          ((float*)D)[(size_t)row * Nc + col] = v;
      }
    }
  }
}

// ---------------- Window attention v5 (best measured) ----------------
// 192 threads (3 waves, 3 mt-tiles each). Swapped QK^T; no-max-sub softmax via __expf
// (fast path). Pipelined: QKT(it+1) in ds_write shadow; SM(it+1) after PV(it);
// setprio around PV MFMA cluster.
__global__ void __launch_bounds__(192) k_attn(const u16* __restrict__ qkv,
                                              const u32* __restrict__ mtab,
                                              u16* __restrict__ obuf) {
  __shared__ u16 k_s[144 * 40];      // [n][d] +8 pad
  __shared__ u16 vT_s[32 * 168];     // [d][k] k padded to 160 (+8)
  __shared__ u16 P_s[3][16 * 168];   // per-wave [q][k], k padded to 160 (+8)

  const int bh = blockIdx.x;
  const int bn = bh >> 4, h = bh & 15;
  const int wid = bn & 63;
  const int tid = threadIdx.x;
  const int wave = tid >> 6, lane = tid & 63;
  const int l15 = lane & 15, g = lane >> 4;
  const f32x4 fzero = {0.f, 0.f, 0.f, 0.f};

  const u16* base = qkv + (size_t)bn * 144 * 1536 + h * 32;
  u16* Pw = &P_s[wave][0];

  bf16x8 qb[3];
  u32 mw[3][5];
#pragma unroll
  for (int it = 0; it < 3; ++it) {
    const int mt = wave + it * 3;
    qb[it] = *(const bf16x8*)(base + (size_t)(mt * 16 + l15) * 1536 + g * 8);
    const u32* mp = mtab + ((size_t)(wid * 144 + mt * 16 + l15) << 3);
#pragma unroll
    for (int wd = 0; wd < 5; ++wd) mw[it][wd] = mp[wd];
  }

  *(u32*)(Pw + l15 * 168 + 144 + g * 4) = 0;
  *(u32*)(Pw + l15 * 168 + 144 + g * 4 + 2) = 0;

  for (int e = tid; e < 576; e += 192) {
    int n = e >> 2, c = e & 3;
    const u16* rowp = base + (size_t)n * 1536 + c * 8;
    u32x4 kv = *(const u32x4*)(rowp + 512);
    u32x4 vv = *(const u32x4*)(rowp + 1024);
    *(u32x4*)(k_s + n * 40 + c * 8) = kv;
#pragma unroll
    for (int t = 0; t < 4; ++t) {
      u32 w = vv[t];
      vT_s[(c * 8 + 2 * t) * 168 + n] = (u16)(w & 0xffffu);
      vT_s[(c * 8 + 2 * t + 1) * 168 + n] = (u16)(w >> 16);
    }
  }
  for (int e = tid; e < 512; e += 192) {
    int d = e >> 4, c = e & 15;
    vT_s[d * 168 + 144 + c] = 0;
  }
  __syncthreads();

  const float scale = 0.17677669529663687f;  // 1/sqrt(32)

  f32x4 accs[9];
  float rinv;

#define QKT(IT)                                                                  \
  {                                                                              \
    _Pragma("unroll") for (int nt = 0; nt < 9; ++nt) {                           \
      bf16x8 kf = *(const bf16x8*)(k_s + (nt * 16 + l15) * 40 + g * 8);          \
      accs[nt] = __builtin_amdgcn_mfma_f32_16x16x32_bf16(kf, qb[IT], fzero, 0, 0, 0); \
    }                                                                            \
  }
#define SM(IT)                                                                   \
  {                                                                              \
    float rsum = 0.f;                                                            \
    _Pragma("unroll") for (int nt = 0; nt < 9; ++nt) {                           \
      const int wd = nt >> 1;                                                    \
      const int shb = (nt & 1) * 16;                                             \
      _Pragma("unroll") for (int j = 0; j < 4; ++j) {                            \
        float e = __expf(accs[nt][j] * scale);                                   \
        u32 bit = (mw[IT][wd] >> (shb + g * 4 + j)) & 1u;                        \
        e = bit ? e : 0.f;                                                       \
        accs[nt][j] = e;                                                         \
        rsum += e;                                                               \
      }                                                                          \
    }                                                                            \
    rsum += __shfl_xor(rsum, 16, 64);                                            \
    rsum += __shfl_xor(rsum, 32, 64);                                            \
    rinv = 1.f / rsum;                                                           \
  }

  QKT(0);
  SM(0);

#pragma unroll
  for (int it = 0; it < 3; ++it) {
    const int mt = wave + it * 3;

#pragma unroll
    for (int nt = 0; nt < 9; ++nt) {
      u32 w0, w1;
      float p0 = accs[nt][0] * rinv, p1 = accs[nt][1] * rinv;
      float p2 = accs[nt][2] * rinv, p3 = accs[nt][3] * rinv;
      asm("v_cvt_pk_bf16_f32 %0, %1, %2" : "=v"(w0) : "v"(p0), "v"(p1));
      asm("v_cvt_pk_bf16_f32 %0, %1, %2" : "=v"(w1) : "v"(p2), "v"(p3));
      *(u32*)(Pw + l15 * 168 + nt * 16 + g * 4) = w0;
      *(u32*)(Pw + l15 * 168 + nt * 16 + g * 4 + 2) = w1;
    }

    if (it == 0) QKT(1);
    if (it == 1) QKT(2);

    asm volatile("s_waitcnt lgkmcnt(0)" ::: "memory");
    __builtin_amdgcn_sched_barrier(0);

    f32x4 acco[2];
    acco[0] = fzero;
    acco[1] = fzero;
    __builtin_amdgcn_s_setprio(1);
#pragma unroll
    for (int kk = 0; kk < 5; ++kk) {
      bf16x8 pa = *(const bf16x8*)(Pw + l15 * 168 + kk * 32 + g * 8);
#pragma unroll
      for (int nt2 = 0; nt2 < 2; ++nt2) {
        bf16x8 b = *(const bf16x8*)(vT_s + (nt2 * 16 + l15) * 168 + kk * 32 + g * 8);
        acco[nt2] = __builtin_amdgcn_mfma_f32_16x16x32_bf16(pa, b, acco[nt2], 0, 0, 0);
      }
    }
    __builtin_amdgcn_s_setprio(0);

    if (it == 0) SM(1);
    if (it == 1) SM(2);

#pragma unroll
    for (int nt2 = 0; nt2 < 2; ++nt2)
#pragma unroll
      for (int j = 0; j < 4; ++j) {
        int r = mt * 16 + g * 4 + j;
        int d = nt2 * 16 + l15;
        obuf[((size_t)bn * 144 + r) * 512 + h * 32 + d] = f2bf_rne(acco[nt2][j]);
      }
  }
#undef QKT
#undef SM
}

extern "C" void kernel_launch(void* const* d_in, const int* in_sizes, int n_in,
                              void* d_out, int out_size, void* d_ws, size_t ws_size,
                              hipStream_t stream) {
  const float* x = (const float*)d_in[0];
  const int* mask = (const int*)d_in[1];
  const float* Wqkv = (const float*)d_in[2];
  const float* bqkv = (const float*)d_in[3];
  const float* Wproj = (const float*)d_in[4];
  const float* bproj = (const float*)d_in[5];
  float* out = (float*)d_out;

  char* ws = (char*)d_ws;
  u32* mtab    = (u32*)(ws + 0);          //     294,912 B
  u16* wqkv_t  = (u16*)(ws + 294912);     //   1,572,864 B
  u16* qkv     = (u16*)(ws + 1867776);    // 113,246,208 B
  u16* obuf    = (u16*)(ws + 115113984);  //  37,748,736 B
  u16* wproj_t = (u16*)(ws + 152862720);  //     524,288 B  (total 153,387,008)

  // 1) fused prep: both weight transposes + mask bitmask (one launch)
  k_prep<<<2560, 256, 0, stream>>>(Wqkv, Wproj, mask, wqkv_t, wproj_t, mtab);
  // 2) qkv = x @ Wqkv + bqkv (bf16 out); A = fp32 x converted in-kernel.
  k_gemm<true, true><<<3456, 256, 0, stream>>>(x, wqkv_t, bqkv, qkv, 1536, 512, 12);
  // 3) window attention (192 threads = 3 waves, pipelined v5)
  k_attn<<<4096, 192, 0, stream>>>(qkv, mtab, obuf);
  // 4) out = O @ Wproj + bproj (fp32 out)
  k_gemm<false, false><<<1152, 256, 0, stream>>>(obuf, wproj_t, bproj, out, 512, 512, 4);
}

// Round 20
// 192.353 us; speedup vs baseline: 1.0103x; 1.0074x over previous
//
#include <hip/hip_runtime.h>

typedef unsigned short u16;
typedef unsigned int u32;
typedef unsigned long long u64;
typedef __attribute__((ext_vector_type(4))) float f32x4;
typedef __attribute__((ext_vector_type(8))) short bf16x8;
typedef __attribute__((ext_vector_type(4))) u32 u32x4;

// ============================================================================
// SESSION LEDGER (R0-R19, best = 189.0 us; noise band +-2-3%):
//   R1 328 -> R2 259.7 (attn occupancy+bitmask) -> R3 245.2 (T2 swizzle, conflicts
//   2.1e7->0) -> R8 204.1 (attn swapped-QKT) -> R10 196.9 (fused convert + v5 attn
//   + ballot mask) -> R16 189.0 (fused prep launch). R17/R18/R19 identical re-runs:
//   193.3 / 194.3 / 193.8 (noise; counters byte-identical).
//   FAILED (do not retry): R4 coarse 8-phase GEMM; R7 counted 4-phase (141);
//   R9 depth-2 A-reg prefetch (scratch spill, WRITE 110->287MB); R11 256x128
//   8-wave (137); R13 full-dbuf 2 blocks/CU (132); R12 attn 9-wave/1-tile (+11);
//   R14 exp2f for __expf (+11: exp2f = PRECISE libm entry without -ffast-math).
//   Mechanism: at 3 blocks/CU the inter-block wave overlap (m114) hides the
//   2-phase drain better than any source-level intra-block pipeline attempted.
//   NOT a HW roofline (MfmaUtil 21%, HBM ~19%): path beyond GEMM1's ~111us is the
//   exact 8-phase derived-waits template (needs interactive asm/A-B iteration).
// ============================================================================

__device__ __forceinline__ u16 f2bf(float f) {
  union { float f; u32 u; } v; v.f = f;
  u32 r = v.u + 0x7fffu + ((v.u >> 16) & 1u);
  return (u16)(r >> 16);
}

// RNE bf16 via HW cvt (1 VALU); store of u16 takes low half directly.
__device__ __forceinline__ u16 f2bf_rne(float f) {
  u32 w;
  asm("v_cvt_pk_bf16_f32 %0, %1, %2" : "=v"(w) : "v"(f), "v"(f));
  return (u16)w;
}

__device__ __forceinline__ void gload_lds16(const u16* g, u16* l) {
  __builtin_amdgcn_global_load_lds((__attribute__((address_space(1))) const void*)g,
                                   (__attribute__((address_space(3))) void*)l,
                                   16, 0, 0);
}

// ---------------- fused prep: weight transposes + mask bitmask in ONE launch ----------------
__device__ __forceinline__ void transpose_tile(const float* __restrict__ W,
                                               u16* __restrict__ Wt, int K, int Nc,
                                               int kb, int nb, int tid) {
  __shared__ u16 t[64][72];  // [k][n], +8 pad
  const int c4 = (tid & 15) * 4;
  const int r0 = tid >> 4;
#pragma unroll
  for (int rr = 0; rr < 4; ++rr) {
    int r = rr * 16 + r0;
    float4 v = *(const float4*)(W + (size_t)(kb + r) * Nc + nb + c4);
    t[r][c4 + 0] = f2bf(v.x);
    t[r][c4 + 1] = f2bf(v.y);
    t[r][c4 + 2] = f2bf(v.z);
    t[r][c4 + 3] = f2bf(v.w);
  }
  __syncthreads();
  const int c8 = (tid & 7) * 8;
  const int rn = tid >> 3;
#pragma unroll
  for (int rr = 0; rr < 2; ++rr) {
    int n = rr * 32 + rn;
    u16 tmp[8];
#pragma unroll
    for (int j = 0; j < 8; ++j) tmp[j] = t[c8 + j][n];
    *(u32x4*)(Wt + (size_t)(nb + n) * K + kb + c8) = *(const u32x4*)tmp;
  }
}

__global__ void __launch_bounds__(256) k_prep(const float* __restrict__ Wqkv,
                                              const float* __restrict__ Wproj,
                                              const int* __restrict__ mask,
                                              u16* __restrict__ wqkv_t,
                                              u16* __restrict__ wproj_t,
                                              u32* __restrict__ mtab) {
  const int b = blockIdx.x;
  const int tid = threadIdx.x;
  if (b < 192) {
    transpose_tile(Wqkv, wqkv_t, 512, 1536, (b & 7) * 64, (b >> 3) * 64, tid);
  } else if (b < 256) {
    const int bb = b - 192;  // 8 x 8 grid
    transpose_tile(Wproj, wproj_t, 512, 512, (bb & 7) * 64, (bb >> 3) * 64, tid);
  } else {
    const int row = (b - 256) * 4 + (tid >> 6);  // 9216 rows = 64*144
    const int lane = tid & 63;
    const int* base = mask + (size_t)row * 144;
    u64 b01 = __ballot(base[lane] != 0);        // cols 0..63
    u64 b23 = __ballot(base[64 + lane] != 0);   // cols 64..127
    int v4 = (lane < 16) ? base[128 + lane] : 0;
    u64 b4 = __ballot(v4 != 0);                 // cols 128..143
    if (lane == 0) {
      u32* o = mtab + (size_t)row * 8;
      o[0] = (u32)b01; o[1] = (u32)(b01 >> 32);
      o[2] = (u32)b23; o[3] = (u32)(b23 >> 32);
      o[4] = (u32)b4;  o[5] = 0; o[6] = 0; o[7] = 0;
    }
  }
}

// ---------------- GEMM (best measured): 128x128, BK=64, 4 waves, 3 blocks/CU ----------------
// A: global (fp32->cvt | bf16) -> regs (issued iter t-1) -> ds_write into padded As[128][68].
// B: gload_lds, double-buffered, chunk-XOR source swizzle (0 conflicts).
// One vmcnt(0)+lgkmcnt(0) per iter, raw s_barrier. LDS 50,176 B -> 3 blocks/CU.
template <bool OUT_BF16, bool A_FP32>
__global__ void __launch_bounds__(256, 3) k_gemm(const void* __restrict__ Ap,
                                                 const u16* __restrict__ Bt,
                                                 const float* __restrict__ bias,
                                                 void* __restrict__ D,
                                                 int Nc, int K, int NB) {
  __shared__ u16 As[128 * 68];      // row stride 68 u16 = 136 B (pad +4)
  __shared__ u16 Bs[2][128 * 64];   // linear dest, chunk-XOR swizzled source
  const int tid = threadIdx.x;
  const int wave = tid >> 6, lane = tid & 63;
  const int wr = wave >> 1, wc = wave & 1;
  const int l15 = lane & 15, g = lane >> 4;
  const int sx = l15 & 7;
  const f32x4 fzero = {0.f, 0.f, 0.f, 0.f};

  const int cpx = gridDim.x >> 3;
  const int swz = (blockIdx.x & 7) * cpx + (blockIdx.x >> 3);
  const int bm = swz / NB, bn = swz % NB;

  const u16* Bb = Bt + (size_t)bn * 128 * K;

  int rr[4], cc[4];
#pragma unroll
  for (int i = 0; i < 4; ++i) {
    int e = i * 256 + tid;
    rr[i] = e >> 3;
    cc[i] = e & 7;
  }

  f32x4 acc[4][4];
#pragma unroll
  for (int m = 0; m < 4; ++m)
#pragma unroll
    for (int n = 0; n < 4; ++n) acc[m][n] = fzero;

  f32x4 areg[8];
  u32x4 aregb[4];

  auto A_LOAD = [&](int ks) {
    if constexpr (A_FP32) {
      const float* Af = (const float*)Ap;
#pragma unroll
      for (int i = 0; i < 4; ++i) {
        const float* p = Af + (size_t)(bm * 128 + rr[i]) * K + ks + cc[i] * 8;
        areg[2 * i] = *(const f32x4*)(p);
        areg[2 * i + 1] = *(const f32x4*)(p + 4);
      }
    } else {
      const u16* Ab = (const u16*)Ap + (size_t)bm * 128 * K;
#pragma unroll
      for (int i = 0; i < 4; ++i)
        aregb[i] = *(const u32x4*)(Ab + (size_t)rr[i] * K + ks + cc[i] * 8);
    }
  };

  auto A_WRITE = [&]() {
#pragma unroll
    for (int i = 0; i < 4; ++i) {
      u32x4 wv;
      if constexpr (A_FP32) {
        u32 w0, w1, w2, w3;
        asm("v_cvt_pk_bf16_f32 %0, %1, %2" : "=v"(w0) : "v"(areg[2 * i][0]), "v"(areg[2 * i][1]));
        asm("v_cvt_pk_bf16_f32 %0, %1, %2" : "=v"(w1) : "v"(areg[2 * i][2]), "v"(areg[2 * i][3]));
        asm("v_cvt_pk_bf16_f32 %0, %1, %2" : "=v"(w2) : "v"(areg[2 * i + 1][0]), "v"(areg[2 * i + 1][1]));
        asm("v_cvt_pk_bf16_f32 %0, %1, %2" : "=v"(w3) : "v"(areg[2 * i + 1][2]), "v"(areg[2 * i + 1][3]));
        wv[0] = w0; wv[1] = w1; wv[2] = w2; wv[3] = w3;
      } else {
        wv = aregb[i];
      }
      *(u32x4*)(&As[rr[i] * 68 + cc[i] * 8]) = wv;
    }
  };

  auto B_STAGE = [&](int buf, int ks) {
#pragma unroll
    for (int i = 0; i < 4; ++i) {
      int cs = cc[i] ^ (rr[i] & 7);
      gload_lds16(Bb + (size_t)rr[i] * K + ks + (cs << 3), &Bs[buf][(i * 256 + tid) * 8]);
    }
  };

  auto COMPUTE = [&](int buf) {
#pragma unroll
    for (int kk = 0; kk < 2; ++kk) {
      bf16x8 a[4], b[4];
#pragma unroll
      for (int m = 0; m < 4; ++m)
        a[m] = *(const bf16x8*)(&As[(wr * 64 + m * 16 + l15) * 68 + (kk * 4 + g) * 8]);
#pragma unroll
      for (int n = 0; n < 4; ++n)
        b[n] = *(const bf16x8*)(&Bs[buf][(wc * 64 + n * 16 + l15) * 64 + (((kk * 4 + g) ^ sx) << 3)]);
#pragma unroll
      for (int m = 0; m < 4; ++m)
#pragma unroll
        for (int n = 0; n < 4; ++n)
          acc[m][n] = __builtin_amdgcn_mfma_f32_16x16x32_bf16(a[m], b[n], acc[m][n], 0, 0, 0);
    }
  };

  const int nt = K >> 6;
  A_LOAD(0);
  B_STAGE(0, 0);
  int cur = 0;
  for (int t = 0; t < nt; ++t) {
    asm volatile("s_waitcnt vmcnt(0)" ::: "memory");
    __builtin_amdgcn_sched_barrier(0);
    if (t + 1 < nt) B_STAGE(cur ^ 1, (t + 1) << 6);
    A_WRITE();
    if (t + 1 < nt) A_LOAD((t + 1) << 6);
    asm volatile("s_waitcnt lgkmcnt(0)" ::: "memory");
    __builtin_amdgcn_sched_barrier(0);
    __builtin_amdgcn_s_barrier();
    __builtin_amdgcn_sched_barrier(0);
    COMPUTE(cur);
    __builtin_amdgcn_sched_barrier(0);
    if (t + 1 < nt) __builtin_amdgcn_s_barrier();
    cur ^= 1;
  }

  const int row0 = bm * 128 + wr * 64;
  const int col0 = bn * 128 + wc * 64;
#pragma unroll
  for (int m = 0; m < 4; ++m) {
#pragma unroll
    for (int n = 0; n < 4; ++n) {
      int col = col0 + n * 16 + l15;
      float bv = bias[col];
#pragma unroll
      for (int j = 0; j < 4; ++j) {
        int row = row0 + m * 16 + g * 4 + j;
        float v = acc[m][n][j] + bv;
        if constexpr (OUT_BF16)
          ((u16*)D)[(size_t)row * Nc + col] = f2bf_rne(v);
        else
          ((float*)D)[(size_t)row * Nc + col] = v;
      }
    }
  }
}

// ---------------- Window attention v5 (best measured) ----------------
// 192 threads (3 waves, 3 mt-tiles each). Swapped QK^T; no-max-sub softmax via __expf
// (fast path). Pipelined: QKT(it+1) in ds_write shadow; SM(it+1) after PV(it);
// setprio around PV MFMA cluster.
__global__ void __launch_bounds__(192) k_attn(const u16* __restrict__ qkv,
                                              const u32* __restrict__ mtab,
                                              u16* __restrict__ obuf) {
  __shared__ u16 k_s[144 * 40];      // [n][d] +8 pad
  __shared__ u16 vT_s[32 * 168];     // [d][k] k padded to 160 (+8)
  __shared__ u16 P_s[3][16 * 168];   // per-wave [q][k], k padded to 160 (+8)

  const int bh = blockIdx.x;
  const int bn = bh >> 4, h = bh & 15;
  const int wid = bn & 63;
  const int tid = threadIdx.x;
  const int wave = tid >> 6, lane = tid & 63;
  const int l15 = lane & 15, g = lane >> 4;
  const f32x4 fzero = {0.f, 0.f, 0.f, 0.f};

  const u16* base = qkv + (size_t)bn * 144 * 1536 + h * 32;
  u16* Pw = &P_s[wave][0];

  bf16x8 qb[3];
  u32 mw[3][5];
#pragma unroll
  for (int it = 0; it < 3; ++it) {
    const int mt = wave + it * 3;
    qb[it] = *(const bf16x8*)(base + (size_t)(mt * 16 + l15) * 1536 + g * 8);
    const u32* mp = mtab + ((size_t)(wid * 144 + mt * 16 + l15) << 3);
#pragma unroll
    for (int wd = 0; wd < 5; ++wd) mw[it][wd] = mp[wd];
  }

  *(u32*)(Pw + l15 * 168 + 144 + g * 4) = 0;
  *(u32*)(Pw + l15 * 168 + 144 + g * 4 + 2) = 0;

  for (int e = tid; e < 576; e += 192) {
    int n = e >> 2, c = e & 3;
    const u16* rowp = base + (size_t)n * 1536 + c * 8;
    u32x4 kv = *(const u32x4*)(rowp + 512);
    u32x4 vv = *(const u32x4*)(rowp + 1024);
    *(u32x4*)(k_s + n * 40 + c * 8) = kv;
#pragma unroll
    for (int t = 0; t < 4; ++t) {
      u32 w = vv[t];
      vT_s[(c * 8 + 2 * t) * 168 + n] = (u16)(w & 0xffffu);
      vT_s[(c * 8 + 2 * t + 1) * 168 + n] = (u16)(w >> 16);
    }
  }
  for (int e = tid; e < 512; e += 192) {
    int d = e >> 4, c = e & 15;
    vT_s[d * 168 + 144 + c] = 0;
  }
  __syncthreads();

  const float scale = 0.17677669529663687f;  // 1/sqrt(32)

  f32x4 accs[9];
  float rinv;

#define QKT(IT)                                                                  \
  {                                                                              \
    _Pragma("unroll") for (int nt = 0; nt < 9; ++nt) {                           \
      bf16x8 kf = *(const bf16x8*)(k_s + (nt * 16 + l15) * 40 + g * 8);          \
      accs[nt] = __builtin_amdgcn_mfma_f32_16x16x32_bf16(kf, qb[IT], fzero, 0, 0, 0); \
    }                                                                            \
  }
#define SM(IT)                                                                   \
  {                                                                              \
    float rsum = 0.f;                                                            \
    _Pragma("unroll") for (int nt = 0; nt < 9; ++nt) {                           \
      const int wd = nt >> 1;                                                    \
      const int shb = (nt & 1) * 16;                                             \
      _Pragma("unroll") for (int j = 0; j < 4; ++j) {                            \
        float e = __expf(accs[nt][j] * scale);                                   \
        u32 bit = (mw[IT][wd] >> (shb + g * 4 + j)) & 1u;                        \
        e = bit ? e : 0.f;                                                       \
        accs[nt][j] = e;                                                         \
        rsum += e;                                                               \
      }                                                                          \
    }                                                                            \
    rsum += __shfl_xor(rsum, 16, 64);                                            \
    rsum += __shfl_xor(rsum, 32, 64);                                            \
    rinv = 1.f / rsum;                                                           \
  }

  QKT(0);
  SM(0);

#pragma unroll
  for (int it = 0; it < 3; ++it) {
    const int mt = wave + it * 3;

#pragma unroll
    for (int nt = 0; nt < 9; ++nt) {
      u32 w0, w1;
      float p0 = accs[nt][0] * rinv, p1 = accs[nt][1] * rinv;
      float p2 = accs[nt][2] * rinv, p3 = accs[nt][3] * rinv;
      asm("v_cvt_pk_bf16_f32 %0, %1, %2" : "=v"(w0) : "v"(p0), "v"(p1));
      asm("v_cvt_pk_bf16_f32 %0, %1, %2" : "=v"(w1) : "v"(p2), "v"(p3));
      *(u32*)(Pw + l15 * 168 + nt * 16 + g * 4) = w0;
      *(u32*)(Pw + l15 * 168 + nt * 16 + g * 4 + 2) = w1;
    }

    if (it == 0) QKT(1);
    if (it == 1) QKT(2);

    asm volatile("s_waitcnt lgkmcnt(0)" ::: "memory");
    __builtin_amdgcn_sched_barrier(0);

    f32x4 acco[2];
    acco[0] = fzero;
    acco[1] = fzero;
    __builtin_amdgcn_s_setprio(1);
#pragma unroll
    for (int kk = 0; kk < 5; ++kk) {
      bf16x8 pa = *(const bf16x8*)(Pw + l15 * 168 + kk * 32 + g * 8);
#pragma unroll
      for (int nt2 = 0; nt2 < 2; ++nt2) {
        bf16x8 b = *(const bf16x8*)(vT_s + (nt2 * 16 + l15) * 168 + kk * 32 + g * 8);
        acco[nt2] = __builtin_amdgcn_mfma_f32_16x16x32_bf16(pa, b, acco[nt2], 0, 0, 0);
      }
    }
    __builtin_amdgcn_s_setprio(0);

    if (it == 0) SM(1);
    if (it == 1) SM(2);

#pragma unroll
    for (int nt2 = 0; nt2 < 2; ++nt2)
#pragma unroll
      for (int j = 0; j < 4; ++j) {
        int r = mt * 16 + g * 4 + j;
        int d = nt2 * 16 + l15;
        obuf[((size_t)bn * 144 + r) * 512 + h * 32 + d] = f2bf_rne(acco[nt2][j]);
      }
  }
#undef QKT
#undef SM
}

extern "C" void kernel_launch(void* const* d_in, const int* in_sizes, int n_in,
                              void* d_out, int out_size, void* d_ws, size_t ws_size,
                              hipStream_t stream) {
  const float* x = (const float*)d_in[0];
  const int* mask = (const int*)d_in[1];
  const float* Wqkv = (const float*)d_in[2];
  const float* bqkv = (const float*)d_in[3];
  const float* Wproj = (const float*)d_in[4];
  const float* bproj = (const float*)d_in[5];
  float* out = (float*)d_out;

  char* ws = (char*)d_ws;
  u32* mtab    = (u32*)(ws + 0);          //     294,912 B
  u16* wqkv_t  = (u16*)(ws + 294912);     //   1,572,864 B
  u16* qkv     = (u16*)(ws + 1867776);    // 113,246,208 B
  u16* obuf    = (u16*)(ws + 115113984);  //  37,748,736 B
  u16* wproj_t = (u16*)(ws + 152862720);  //     524,288 B  (total 153,387,008)

  // 1) fused prep: both weight transposes + mask bitmask (one launch)
  k_prep<<<2560, 256, 0, stream>>>(Wqkv, Wproj, mask, wqkv_t, wproj_t, mtab);
  // 2) qkv = x @ Wqkv + bqkv (bf16 out); A = fp32 x converted in-kernel.
  k_gemm<true, true><<<3456, 256, 0, stream>>>(x, wqkv_t, bqkv, qkv, 1536, 512, 12);
  // 3) window attention (192 threads = 3 waves, pipelined v5)
  k_attn<<<4096, 192, 0, stream>>>(qkv, mtab, obuf);
  // 4) out = O @ Wproj + bproj (fp32 out)
  k_gemm<false, false><<<1152, 256, 0, stream>>>(obuf, wproj_t, bproj, out, 512, 512, 4);
}

// Round 21
// 188.377 us; speedup vs baseline: 1.0316x; 1.0211x over previous
//
#include <hip/hip_runtime.h>

typedef unsigned short u16;
typedef unsigned int u32;
typedef unsigned long long u64;
typedef __attribute__((ext_vector_type(4))) float f32x4;
typedef __attribute__((ext_vector_type(8))) short bf16x8;
typedef __attribute__((ext_vector_type(4))) u32 u32x4;

// ============================================================================
// SESSION LEDGER (R0-R20, best = 189.0 us; noise band +-2-3%):
//   R1 328 -> R2 259.7 (attn occupancy+bitmask) -> R3 245.2 (T2 swizzle, conflicts
//   2.1e7->0) -> R8 204.1 (attn swapped-QKT) -> R10 196.9 (fused convert + v5 attn
//   + ballot mask) -> R16 189.0 (fused prep launch). R17-R20 identical re-runs:
//   193.3 / 194.3 / 193.8 / 192.4 (noise; counters byte-identical).
//   FAILED (do not retry): R4 coarse 8-phase GEMM; R7 counted 4-phase (141);
//   R9 depth-2 A-reg prefetch (scratch spill, WRITE 110->287MB); R11 256x128
//   8-wave (137); R13 full-dbuf 2 blocks/CU (132); R12 attn 9-wave/1-tile (+11);
//   R14 exp2f for __expf (+11: exp2f = PRECISE libm entry without -ffast-math).
//   Mechanism: at 3 blocks/CU the inter-block wave overlap (m114) hides the
//   2-phase drain better than any source-level intra-block pipeline attempted.
//   NOT a HW roofline (MfmaUtil 21%, HBM ~19%): path beyond GEMM1's ~111us is the
//   exact 8-phase derived-waits template (needs interactive asm/A-B iteration).
// ============================================================================

__device__ __forceinline__ u16 f2bf(float f) {
  union { float f; u32 u; } v; v.f = f;
  u32 r = v.u + 0x7fffu + ((v.u >> 16) & 1u);
  return (u16)(r >> 16);
}

// RNE bf16 via HW cvt (1 VALU); store of u16 takes low half directly.
__device__ __forceinline__ u16 f2bf_rne(float f) {
  u32 w;
  asm("v_cvt_pk_bf16_f32 %0, %1, %2" : "=v"(w) : "v"(f), "v"(f));
  return (u16)w;
}

__device__ __forceinline__ void gload_lds16(const u16* g, u16* l) {
  __builtin_amdgcn_global_load_lds((__attribute__((address_space(1))) const void*)g,
                                   (__attribute__((address_space(3))) void*)l,
                                   16, 0, 0);
}

// ---------------- fused prep: weight transposes + mask bitmask in ONE launch ----------------
__device__ __forceinline__ void transpose_tile(const float* __restrict__ W,
                                               u16* __restrict__ Wt, int K, int Nc,
                                               int kb, int nb, int tid) {
  __shared__ u16 t[64][72];  // [k][n], +8 pad
  const int c4 = (tid & 15) * 4;
  const int r0 = tid >> 4;
#pragma unroll
  for (int rr = 0; rr < 4; ++rr) {
    int r = rr * 16 + r0;
    float4 v = *(const float4*)(W + (size_t)(kb + r) * Nc + nb + c4);
    t[r][c4 + 0] = f2bf(v.x);
    t[r][c4 + 1] = f2bf(v.y);
    t[r][c4 + 2] = f2bf(v.z);
    t[r][c4 + 3] = f2bf(v.w);
  }
  __syncthreads();
  const int c8 = (tid & 7) * 8;
  const int rn = tid >> 3;
#pragma unroll
  for (int rr = 0; rr < 2; ++rr) {
    int n = rr * 32 + rn;
    u16 tmp[8];
#pragma unroll
    for (int j = 0; j < 8; ++j) tmp[j] = t[c8 + j][n];
    *(u32x4*)(Wt + (size_t)(nb + n) * K + kb + c8) = *(const u32x4*)tmp;
  }
}

__global__ void __launch_bounds__(256) k_prep(const float* __restrict__ Wqkv,
                                              const float* __restrict__ Wproj,
                                              const int* __restrict__ mask,
                                              u16* __restrict__ wqkv_t,
                                              u16* __restrict__ wproj_t,
                                              u32* __restrict__ mtab) {
  const int b = blockIdx.x;
  const int tid = threadIdx.x;
  if (b < 192) {
    transpose_tile(Wqkv, wqkv_t, 512, 1536, (b & 7) * 64, (b >> 3) * 64, tid);
  } else if (b < 256) {
    const int bb = b - 192;  // 8 x 8 grid
    transpose_tile(Wproj, wproj_t, 512, 512, (bb & 7) * 64, (bb >> 3) * 64, tid);
  } else {
    const int row = (b - 256) * 4 + (tid >> 6);  // 9216 rows = 64*144
    const int lane = tid & 63;
    const int* base = mask + (size_t)row * 144;
    u64 b01 = __ballot(base[lane] != 0);        // cols 0..63
    u64 b23 = __ballot(base[64 + lane] != 0);   // cols 64..127
    int v4 = (lane < 16) ? base[128 + lane] : 0;
    u64 b4 = __ballot(v4 != 0);                 // cols 128..143
    if (lane == 0) {
      u32* o = mtab + (size_t)row * 8;
      o[0] = (u32)b01; o[1] = (u32)(b01 >> 32);
      o[2] = (u32)b23; o[3] = (u32)(b23 >> 32);
      o[4] = (u32)b4;  o[5] = 0; o[6] = 0; o[7] = 0;
    }
  }
}

// ---------------- GEMM (best measured): 128x128, BK=64, 4 waves, 3 blocks/CU ----------------
// A: global (fp32->cvt | bf16) -> regs (issued iter t-1) -> ds_write into padded As[128][68].
// B: gload_lds, double-buffered, chunk-XOR source swizzle (0 conflicts).
// One vmcnt(0)+lgkmcnt(0) per iter, raw s_barrier. LDS 50,176 B -> 3 blocks/CU.
template <bool OUT_BF16, bool A_FP32>
__global__ void __launch_bounds__(256, 3) k_gemm(const void* __restrict__ Ap,
                                                 const u16* __restrict__ Bt,
                                                 const float* __restrict__ bias,
                                                 void* __restrict__ D,
                                                 int Nc, int K, int NB) {
  __shared__ u16 As[128 * 68];      // row stride 68 u16 = 136 B (pad +4)
  __shared__ u16 Bs[2][128 * 64];   // linear dest, chunk-XOR swizzled source
  const int tid = threadIdx.x;
  const int wave = tid >> 6, lane = tid & 63;
  const int wr = wave >> 1, wc = wave & 1;
  const int l15 = lane & 15, g = lane >> 4;
  const int sx = l15 & 7;
  const f32x4 fzero = {0.f, 0.f, 0.f, 0.f};

  const int cpx = gridDim.x >> 3;
  const int swz = (blockIdx.x & 7) * cpx + (blockIdx.x >> 3);
  const int bm = swz / NB, bn = swz % NB;

  const u16* Bb = Bt + (size_t)bn * 128 * K;

  int rr[4], cc[4];
#pragma unroll
  for (int i = 0; i < 4; ++i) {
    int e = i * 256 + tid;
    rr[i] = e >> 3;
    cc[i] = e & 7;
  }

  f32x4 acc[4][4];
#pragma unroll
  for (int m = 0; m < 4; ++m)
#pragma unroll
    for (int n = 0; n < 4; ++n) acc[m][n] = fzero;

  f32x4 areg[8];
  u32x4 aregb[4];

  auto A_LOAD = [&](int ks) {
    if constexpr (A_FP32) {
      const float* Af = (const float*)Ap;
#pragma unroll
      for (int i = 0; i < 4; ++i) {
        const float* p = Af + (size_t)(bm * 128 + rr[i]) * K + ks + cc[i] * 8;
        areg[2 * i] = *(const f32x4*)(p);
        areg[2 * i + 1] = *(const f32x4*)(p + 4);
      }
    } else {
      const u16* Ab = (const u16*)Ap + (size_t)bm * 128 * K;
#pragma unroll
      for (int i = 0; i < 4; ++i)
        aregb[i] = *(const u32x4*)(Ab + (size_t)rr[i] * K + ks + cc[i] * 8);
    }
  };

  auto A_WRITE = [&]() {
#pragma unroll
    for (int i = 0; i < 4; ++i) {
      u32x4 wv;
      if constexpr (A_FP32) {
        u32 w0, w1, w2, w3;
        asm("v_cvt_pk_bf16_f32 %0, %1, %2" : "=v"(w0) : "v"(areg[2 * i][0]), "v"(areg[2 * i][1]));
        asm("v_cvt_pk_bf16_f32 %0, %1, %2" : "=v"(w1) : "v"(areg[2 * i][2]), "v"(areg[2 * i][3]));
        asm("v_cvt_pk_bf16_f32 %0, %1, %2" : "=v"(w2) : "v"(areg[2 * i + 1][0]), "v"(areg[2 * i + 1][1]));
        asm("v_cvt_pk_bf16_f32 %0, %1, %2" : "=v"(w3) : "v"(areg[2 * i + 1][2]), "v"(areg[2 * i + 1][3]));
        wv[0] = w0; wv[1] = w1; wv[2] = w2; wv[3] = w3;
      } else {
        wv = aregb[i];
      }
      *(u32x4*)(&As[rr[i] * 68 + cc[i] * 8]) = wv;
    }
  };

  auto B_STAGE = [&](int buf, int ks) {
#pragma unroll
    for (int i = 0; i < 4; ++i) {
      int cs = cc[i] ^ (rr[i] & 7);
      gload_lds16(Bb + (size_t)rr[i] * K + ks + (cs << 3), &Bs[buf][(i * 256 + tid) * 8]);
    }
  };

  auto COMPUTE = [&](int buf) {
#pragma unroll
    for (int kk = 0; kk < 2; ++kk) {
      bf16x8 a[4], b[4];
#pragma unroll
      for (int m = 0; m < 4; ++m)
        a[m] = *(const bf16x8*)(&As[(wr * 64 + m * 16 + l15) * 68 + (kk * 4 + g) * 8]);
#pragma unroll
      for (int n = 0; n < 4; ++n)
        b[n] = *(const bf16x8*)(&Bs[buf][(wc * 64 + n * 16 + l15) * 64 + (((kk * 4 + g) ^ sx) << 3)]);
#pragma unroll
      for (int m = 0; m < 4; ++m)
#pragma unroll
        for (int n = 0; n < 4; ++n)
          acc[m][n] = __builtin_amdgcn_mfma_f32_16x16x32_bf16(a[m], b[n], acc[m][n], 0, 0, 0);
    }
  };

  const int nt = K >> 6;
  A_LOAD(0);
  B_STAGE(0, 0);
  int cur = 0;
  for (int t = 0; t < nt; ++t) {
    asm volatile("s_waitcnt vmcnt(0)" ::: "memory");
    __builtin_amdgcn_sched_barrier(0);
    if (t + 1 < nt) B_STAGE(cur ^ 1, (t + 1) << 6);
    A_WRITE();
    if (t + 1 < nt) A_LOAD((t + 1) << 6);
    asm volatile("s_waitcnt lgkmcnt(0)" ::: "memory");
    __builtin_amdgcn_sched_barrier(0);
    __builtin_amdgcn_s_barrier();
    __builtin_amdgcn_sched_barrier(0);
    COMPUTE(cur);
    __builtin_amdgcn_sched_barrier(0);
    if (t + 1 < nt) __builtin_amdgcn_s_barrier();
    cur ^= 1;
  }

  const int row0 = bm * 128 + wr * 64;
  const int col0 = bn * 128 + wc * 64;
#pragma unroll
  for (int m = 0; m < 4; ++m) {
#pragma unroll
    for (int n = 0; n < 4; ++n) {
      int col = col0 + n * 16 + l15;
      float bv = bias[col];
#pragma unroll
      for (int j = 0; j < 4; ++j) {
        int row = row0 + m * 16 + g * 4 + j;
        float v = acc[m][n][j] + bv;
        if constexpr (OUT_BF16)
          ((u16*)D)[(size_t)row * Nc + col] = f2bf_rne(v);
        else
          ((float*)D)[(size_t)row * Nc + col] = v;
      }
    }
  }
}

// ---------------- Window attention v5 (best measured) ----------------
// 192 threads (3 waves, 3 mt-tiles each). Swapped QK^T; no-max-sub softmax via __expf
// (fast path). Pipelined: QKT(it+1) in ds_write shadow; SM(it+1) after PV(it);
// setprio around PV MFMA cluster.
__global__ void __launch_bounds__(192) k_attn(const u16* __restrict__ qkv,
                                              const u32* __restrict__ mtab,
                                              u16* __restrict__ obuf) {
  __shared__ u16 k_s[144 * 40];      // [n][d] +8 pad
  __shared__ u16 vT_s[32 * 168];     // [d][k] k padded to 160 (+8)
  __shared__ u16 P_s[3][16 * 168];   // per-wave [q][k], k padded to 160 (+8)

  const int bh = blockIdx.x;
  const int bn = bh >> 4, h = bh & 15;
  const int wid = bn & 63;
  const int tid = threadIdx.x;
  const int wave = tid >> 6, lane = tid & 63;
  const int l15 = lane & 15, g = lane >> 4;
  const f32x4 fzero = {0.f, 0.f, 0.f, 0.f};

  const u16* base = qkv + (size_t)bn * 144 * 1536 + h * 32;
  u16* Pw = &P_s[wave][0];

  bf16x8 qb[3];
  u32 mw[3][5];
#pragma unroll
  for (int it = 0; it < 3; ++it) {
    const int mt = wave + it * 3;
    qb[it] = *(const bf16x8*)(base + (size_t)(mt * 16 + l15) * 1536 + g * 8);
    const u32* mp = mtab + ((size_t)(wid * 144 + mt * 16 + l15) << 3);
#pragma unroll
    for (int wd = 0; wd < 5; ++wd) mw[it][wd] = mp[wd];
  }

  *(u32*)(Pw + l15 * 168 + 144 + g * 4) = 0;
  *(u32*)(Pw + l15 * 168 + 144 + g * 4 + 2) = 0;

  for (int e = tid; e < 576; e += 192) {
    int n = e >> 2, c = e & 3;
    const u16* rowp = base + (size_t)n * 1536 + c * 8;
    u32x4 kv = *(const u32x4*)(rowp + 512);
    u32x4 vv = *(const u32x4*)(rowp + 1024);
    *(u32x4*)(k_s + n * 40 + c * 8) = kv;
#pragma unroll
    for (int t = 0; t < 4; ++t) {
      u32 w = vv[t];
      vT_s[(c * 8 + 2 * t) * 168 + n] = (u16)(w & 0xffffu);
      vT_s[(c * 8 + 2 * t + 1) * 168 + n] = (u16)(w >> 16);
    }
  }
  for (int e = tid; e < 512; e += 192) {
    int d = e >> 4, c = e & 15;
    vT_s[d * 168 + 144 + c] = 0;
  }
  __syncthreads();

  const float scale = 0.17677669529663687f;  // 1/sqrt(32)

  f32x4 accs[9];
  float rinv;

#define QKT(IT)                                                                  \
  {                                                                              \
    _Pragma("unroll") for (int nt = 0; nt < 9; ++nt) {                           \
      bf16x8 kf = *(const bf16x8*)(k_s + (nt * 16 + l15) * 40 + g * 8);          \
      accs[nt] = __builtin_amdgcn_mfma_f32_16x16x32_bf16(kf, qb[IT], fzero, 0, 0, 0); \
    }                                                                            \
  }
#define SM(IT)                                                                   \
  {                                                                              \
    float rsum = 0.f;                                                            \
    _Pragma("unroll") for (int nt = 0; nt < 9; ++nt) {                           \
      const int wd = nt >> 1;                                                    \
      const int shb = (nt & 1) * 16;                                             \
      _Pragma("unroll") for (int j = 0; j < 4; ++j) {                            \
        float e = __expf(accs[nt][j] * scale);                                   \
        u32 bit = (mw[IT][wd] >> (shb + g * 4 + j)) & 1u;                        \
        e = bit ? e : 0.f;                                                       \
        accs[nt][j] = e;                                                         \
        rsum += e;                                                               \
      }                                                                          \
    }                                                                            \
    rsum += __shfl_xor(rsum, 16, 64);                                            \
    rsum += __shfl_xor(rsum, 32, 64);                                            \
    rinv = 1.f / rsum;                                                           \
  }

  QKT(0);
  SM(0);

#pragma unroll
  for (int it = 0; it < 3; ++it) {
    const int mt = wave + it * 3;

#pragma unroll
    for (int nt = 0; nt < 9; ++nt) {
      u32 w0, w1;
      float p0 = accs[nt][0] * rinv, p1 = accs[nt][1] * rinv;
      float p2 = accs[nt][2] * rinv, p3 = accs[nt][3] * rinv;
      asm("v_cvt_pk_bf16_f32 %0, %1, %2" : "=v"(w0) : "v"(p0), "v"(p1));
      asm("v_cvt_pk_bf16_f32 %0, %1, %2" : "=v"(w1) : "v"(p2), "v"(p3));
      *(u32*)(Pw + l15 * 168 + nt * 16 + g * 4) = w0;
      *(u32*)(Pw + l15 * 168 + nt * 16 + g * 4 + 2) = w1;
    }

    if (it == 0) QKT(1);
    if (it == 1) QKT(2);

    asm volatile("s_waitcnt lgkmcnt(0)" ::: "memory");
    __builtin_amdgcn_sched_barrier(0);

    f32x4 acco[2];
    acco[0] = fzero;
    acco[1] = fzero;
    __builtin_amdgcn_s_setprio(1);
#pragma unroll
    for (int kk = 0; kk < 5; ++kk) {
      bf16x8 pa = *(const bf16x8*)(Pw + l15 * 168 + kk * 32 + g * 8);
#pragma unroll
      for (int nt2 = 0; nt2 < 2; ++nt2) {
        bf16x8 b = *(const bf16x8*)(vT_s + (nt2 * 16 + l15) * 168 + kk * 32 + g * 8);
        acco[nt2] = __builtin_amdgcn_mfma_f32_16x16x32_bf16(pa, b, acco[nt2], 0, 0, 0);
      }
    }
    __builtin_amdgcn_s_setprio(0);

    if (it == 0) SM(1);
    if (it == 1) SM(2);

#pragma unroll
    for (int nt2 = 0; nt2 < 2; ++nt2)
#pragma unroll
      for (int j = 0; j < 4; ++j) {
        int r = mt * 16 + g * 4 + j;
        int d = nt2 * 16 + l15;
        obuf[((size_t)bn * 144 + r) * 512 + h * 32 + d] = f2bf_rne(acco[nt2][j]);
      }
  }
#undef QKT
#undef SM
}

extern "C" void kernel_launch(void* const* d_in, const int* in_sizes, int n_in,
                              void* d_out, int out_size, void* d_ws, size_t ws_size,
                              hipStream_t stream) {
  const float* x = (const float*)d_in[0];
  const int* mask = (const int*)d_in[1];
  const float* Wqkv = (const float*)d_in[2];
  const float* bqkv = (const float*)d_in[3];
  const float* Wproj = (const float*)d_in[4];
  const float* bproj = (const float*)d_in[5];
  float* out = (float*)d_out;

  char* ws = (char*)d_ws;
  u32* mtab    = (u32*)(ws + 0);          //     294,912 B
  u16* wqkv_t  = (u16*)(ws + 294912);     //   1,572,864 B
  u16* qkv     = (u16*)(ws + 1867776);    // 113,246,208 B
  u16* obuf    = (u16*)(ws + 115113984);  //  37,748,736 B
  u16* wproj_t = (u16*)(ws + 152862720);  //     524,288 B  (total 153,387,008)

  // 1) fused prep: both weight transposes + mask bitmask (one launch)
  k_prep<<<2560, 256, 0, stream>>>(Wqkv, Wproj, mask, wqkv_t, wproj_t, mtab);
  // 2) qkv = x @ Wqkv + bqkv (bf16 out); A = fp32 x converted in-kernel.
  k_gemm<true, true><<<3456, 256, 0, stream>>>(x, wqkv_t, bqkv, qkv, 1536, 512, 12);
  // 3) window attention (192 threads = 3 waves, pipelined v5)
  k_attn<<<4096, 192, 0, stream>>>(qkv, mtab, obuf);
  // 4) out = O @ Wproj + bproj (fp32 out)
  k_gemm<false, false><<<1152, 256, 0, stream>>>(obuf, wproj_t, bproj, out, 512, 512, 4);
}